// Round 4
// baseline (96.373 us; speedup 1.0000x reference)
//
#include <hip/hip_runtime.h>
#include <hip/hip_bf16.h>
#include <math.h>

// Problem constants (fixed by the reference):
#define B_SZ 1024
#define M_SZ 8192
#define N_SZ 32
#define S_SZ 128

#define MT   256   // m-rows per block (m-split width)
#define BT   32    // b-rows per block
#define NTHR 256
#define NSPLIT 32  // m-splits; grid = NSPLIT x (B/BT) = 32x32 = 1024 = 4 blocks/CU

#define SG_STRIDE 264   // bf16 elems per sG row: 256 + 8 pad (row = 528 B)

typedef __bf16 bf16x8 __attribute__((ext_vector_type(8)));
typedef float  f32x4  __attribute__((ext_vector_type(4)));

#if defined(__has_builtin)
#if __has_builtin(__builtin_amdgcn_exp2f)
#define EXP2F(x) __builtin_amdgcn_exp2f(x)
#else
#define EXP2F(x) exp2f(x)
#endif
#else
#define EXP2F(x) exp2f(x)
#endif

// -pi * log2(e), and its 25x clamp
#define NEG_PI_LOG2E  (-4.5323601722717285f)
#define E_CLAMP       (-113.30900573730469f)

// ---- workspace layout (bytes) ----
#define WS_TSWZ   ((size_t)0)                          // 2 MB  frag-linear bf16 T_hat
#define WS_ZJBF   ((size_t)2 * 1024 * 1024)            // 512 KB bf16 z_j [M][32]
#define WS_DVBF   (WS_ZJBF + (size_t)M_SZ * N_SZ * 2)  // 512 KB bf16 d_hat [M][32]
#define WS_MCONST (WS_DVBF + (size_t)M_SZ * N_SZ * 2)  // 256 KB f32 [M][8] consts
#define WS_ZBF    (WS_MCONST + (size_t)M_SZ * 8 * 4)   // 64 KB  bf16 z [B][32]
#define WS_ZN     (WS_ZBF + (size_t)B_SZ * N_SZ * 2)   // 4 KB   f32 |z_b|^2
#define WS_PART   ((size_t)4 * 1024 * 1024)            // 16 MB  split partials
#define WS_NEED   (WS_PART + (size_t)NSPLIT * B_SZ * S_SZ * 4)   // 20 MB

// ---------------------------------------------------------------------------
// prep (548 blocks x 256):
//  blocks [0,512):   T_hat fp32 [M][S] -> frag-linear bf16 (16 B = one lane's
//                    B-frag: group g -> mc=g>>9, ns=(g>>6)&7, lane=g&63 holds
//                    B[k=mc*32+(lane>>4)*8+j][s=ns*16+(lane&15)])
//  blocks [512,544): per-m: bf16 z_j row, bf16 d_hat row (EPS gate), consts
//                    {A=-pi*log2e*wperp, Cm=A*|zj|^2, Dm=-pi*log2e*wdiff, P0, alpha}
//  blocks [544,548): per-b: bf16 z row + |z|^2
// ---------------------------------------------------------------------------
__global__ __launch_bounds__(256)
void prep_kernel(const float* __restrict__ T,
                 const float* __restrict__ z,
                 const float* __restrict__ zj_in,
                 const float* __restrict__ dv_in,
                 const float* __restrict__ alpha_j,
                 const float* __restrict__ sigma_par,
                 const float* __restrict__ sigma_perp,
                 char* __restrict__ ws)
{
    const int bx = blockIdx.x;
    const int t  = threadIdx.x;

    if (bx < 512) {                       // ---- T swizzle ----
        const int g    = bx * 256 + t;    // 0 .. 131071
        const int mc   = g >> 9;
        const int ns   = (g >> 6) & 7;
        const int lane = g & 63;
        const int c    = lane & 15;
        const int q    = lane >> 4;
        const float* src = T + (size_t)(mc * 32 + q * 8) * S_SZ + ns * 16 + c;
        bf16x8 v;
        #pragma unroll
        for (int j = 0; j < 8; ++j) v[j] = (__bf16)src[(size_t)j * S_SZ];
        *(bf16x8*)(ws + WS_TSWZ + (size_t)g * 16) = v;
    } else if (bx < 544) {                // ---- per-m prep ----
        const int m = (bx - 512) * 256 + t;
        float a[N_SZ], d[N_SZ];
        const float4* a4 = (const float4*)(zj_in + (size_t)m * N_SZ);
        const float4* d4 = (const float4*)(dv_in + (size_t)m * N_SZ);
        #pragma unroll
        for (int i = 0; i < N_SZ / 4; ++i) {
            float4 av = a4[i], dw = d4[i];
            a[4*i+0]=av.x; a[4*i+1]=av.y; a[4*i+2]=av.z; a[4*i+3]=av.w;
            d[4*i+0]=dw.x; d[4*i+1]=dw.y; d[4*i+2]=dw.z; d[4*i+3]=dw.w;
        }
        float zjn = 0.f, dnsq = 0.f, zjd = 0.f;
        #pragma unroll
        for (int n = 0; n < N_SZ; ++n) {
            zjn += a[n]*a[n]; dnsq += d[n]*d[n]; zjd += a[n]*d[n];
        }
        const float dn  = sqrtf(dnsq);
        const float inv = (dn > 1e-6f) ? (1.0f / dn) : 0.0f;   // EPS gate -> proj=0
        __bf16* zjb = (__bf16*)(ws + WS_ZJBF) + (size_t)m * N_SZ;
        __bf16* dvb = (__bf16*)(ws + WS_DVBF) + (size_t)m * N_SZ;
        #pragma unroll
        for (int i = 0; i < 4; ++i) {
            bf16x8 vz, vd;
            #pragma unroll
            for (int j = 0; j < 8; ++j) {
                vz[j] = (__bf16)a[i*8+j];
                vd[j] = (__bf16)(d[i*8+j] * inv);
            }
            *(bf16x8*)(zjb + i*8) = vz;
            *(bf16x8*)(dvb + i*8) = vd;
        }
        const float tiny = 1.1920928955078125e-07f;
        const float sp  = fmaxf(sigma_par[m],  tiny);
        const float spp = fmaxf(sigma_perp[m], tiny);
        const float wperp = 1.0f / (spp * spp);
        const float wdiff = 1.0f / (sp * sp) - wperp;
        const float A = NEG_PI_LOG2E * wperp;
        float* mc8 = (float*)(ws + WS_MCONST) + (size_t)m * 8;
        *(f32x4*)mc8       = (f32x4){A, A * zjn, NEG_PI_LOG2E * wdiff, zjd * inv};
        *(f32x4*)(mc8 + 4) = (f32x4){alpha_j[m], 0.f, 0.f, 0.f};
    } else {                              // ---- per-b prep ----
        const int b = (bx - 544) * 256 + t;   // 0..1023
        float v[N_SZ];
        const float4* z4 = (const float4*)(z + (size_t)b * N_SZ);
        #pragma unroll
        for (int i = 0; i < N_SZ / 4; ++i) {
            float4 w4 = z4[i];
            v[4*i+0]=w4.x; v[4*i+1]=w4.y; v[4*i+2]=w4.z; v[4*i+3]=w4.w;
        }
        float zn = 0.f;
        #pragma unroll
        for (int n = 0; n < N_SZ; ++n) zn += v[n]*v[n];
        __bf16* zb = (__bf16*)(ws + WS_ZBF) + (size_t)b * N_SZ;
        #pragma unroll
        for (int i = 0; i < 4; ++i) {
            bf16x8 vz;
            #pragma unroll
            for (int j = 0; j < 8; ++j) vz[j] = (__bf16)v[i*8+j];
            *(bf16x8*)(zb + i*8) = vz;
        }
        ((float*)(ws + WS_ZN))[b] = zn;
    }
}

// ---------------------------------------------------------------------------
// main: scores via MFMA + exp2 epilogue -> sG (LDS), then PV via MFMA from
// sG x frag-linear Tswz. Partials -> ws (no atomics).
// Grid (NSPLIT=32, B/BT=32) = 1024 blocks = 4/CU. LDS = 16.9 KB.
// Phase 1: wave w -> b-half (w&1), m-tiles (w>>1)*8 + [0,8).
// Phase 2: wave w -> s-tiles {2w,2w+1} x both b-tiles.
// ---------------------------------------------------------------------------
__global__ __launch_bounds__(NTHR, 4)
void cpsf_main_kernel(const char* __restrict__ ws_ro, float* __restrict__ ws_part)
{
    __shared__ __align__(16) __bf16 sG[BT * SG_STRIDE];   // 16.9 KB: gains [b][m_local]

    const int t     = threadIdx.x;
    const int lane  = t & 63;
    const int w     = t >> 6;          // wave 0..3
    const int q     = lane >> 4;       // quad 0..3
    const int c     = lane & 15;
    const int mx    = blockIdx.x;
    const int m0    = mx * MT;
    const int bbase = blockIdx.y * BT;

    const __bf16* zbf   = (const __bf16*)(ws_ro + WS_ZBF);
    const __bf16* zjbf  = (const __bf16*)(ws_ro + WS_ZJBF);
    const __bf16* dvbf  = (const __bf16*)(ws_ro + WS_DVBF);
    const float*  mcst  = (const float*)(ws_ro + WS_MCONST);
    const float*  znp   = (const float*)(ws_ro + WS_ZN);
    const char*   Tswz  = ws_ro + WS_TSWZ;

    // ---- Phase 1: scores + gains ----
    const int wb  = w & 1;             // which 16-row b-half this wave computes
    const int mt0 = (w >> 1) * 8;      // which 8 m-tiles

    // A-frag: z[b = bbase + wb*16 + c][k = q*8 + j]
    const bf16x8 zA  = *(const bf16x8*)(zbf + ((size_t)(bbase + wb*16 + c) * N_SZ + q*8));
    const f32x4  zn4 = *(const f32x4*)(znp + bbase + wb*16 + q*4);

    #pragma unroll 4
    for (int ti = 0; ti < 8; ++ti) {
        const int tile = mt0 + ti;
        const int mg   = m0 + tile*16 + c;
        const bf16x8 bz = *(const bf16x8*)(zjbf + (size_t)mg * N_SZ + q*8);
        const bf16x8 bd = *(const bf16x8*)(dvbf + (size_t)mg * N_SZ + q*8);
        f32x4 s1 = __builtin_amdgcn_mfma_f32_16x16x32_bf16(zA, bz, (f32x4){0.f,0.f,0.f,0.f}, 0, 0, 0);
        f32x4 sd = __builtin_amdgcn_mfma_f32_16x16x32_bf16(zA, bd, (f32x4){0.f,0.f,0.f,0.f}, 0, 0, 0);
        const float* mc8 = mcst + (size_t)mg * 8;
        const f32x4 mc0 = *(const f32x4*)mc8;   // {A, Cm, Dm, P0}
        const float al  = mc8[4];
        #pragma unroll
        for (int reg = 0; reg < 4; ++reg) {
            // e = A*(zn - 2*s1) + Cm + Dm*(sd-P0)^2  (log2 domain, incl -pi)
            const float t1 = fmaf(s1[reg], -2.0f, zn4[reg]);
            float e = fmaf(mc0[0], t1, mc0[1]);
            const float p = sd[reg] - mc0[3];
            e = fmaf(mc0[2] * p, p, e);
            e = fmaxf(e, E_CLAMP);               // q <= 25 clamp
            const float g = al * EXP2F(e);
            // D[row=q*4+reg][col=c] -> gain[b-local = wb*16+q*4+reg][m-local]
            sG[(size_t)(wb*16 + q*4 + reg) * SG_STRIDE + tile*16 + c] = (__bf16)g;
        }
    }
    __syncthreads();

    // ---- Phase 2: PV. Wave w owns s-tiles {2w,2w+1}, both b-tiles. ----
    f32x4 acc[2][2];
    #pragma unroll
    for (int bt = 0; bt < 2; ++bt)
        #pragma unroll
        for (int i = 0; i < 2; ++i) acc[bt][i] = (f32x4){0.f,0.f,0.f,0.f};

    #pragma unroll
    for (int kc = 0; kc < MT / 32; ++kc) {
        const int mc = mx * (MT / 32) + kc;     // global 32-m chunk
        bf16x8 bfr[2];
        #pragma unroll
        for (int i = 0; i < 2; ++i)
            bfr[i] = *(const bf16x8*)(Tswz + ((size_t)(mc*8 + w*2 + i) * 64 + lane) * 16);
        #pragma unroll
        for (int bt = 0; bt < 2; ++bt) {
            // A-frag: G[b = bt*16 + c][k = kc*32 + q*8 + j]
            const bf16x8 a = *(const bf16x8*)((const char*)sG
                              + (size_t)(bt*16 + c) * (SG_STRIDE*2) + kc*64 + q*16);
            #pragma unroll
            for (int i = 0; i < 2; ++i)
                acc[bt][i] = __builtin_amdgcn_mfma_f32_16x16x32_bf16(a, bfr[i], acc[bt][i], 0, 0, 0);
        }
    }

    // ---- Partials: D[row=q*4+reg][col=c]; plain coalesced stores. ----
    #pragma unroll
    for (int bt = 0; bt < 2; ++bt) {
        float* part = ws_part + (size_t)mx * (B_SZ * S_SZ)
                    + (size_t)(bbase + bt*16 + q*4) * S_SZ + w*32 + c;
        #pragma unroll
        for (int i = 0; i < 2; ++i)
            #pragma unroll
            for (int reg = 0; reg < 4; ++reg)
                part[(size_t)reg * S_SZ + i*16] = acc[bt][i][reg];
    }
}

// ---------------------------------------------------------------------------
// reduce: out[i] = sum over NSPLIT partials. 512 blocks (2/CU), coalesced.
// ---------------------------------------------------------------------------
__global__ __launch_bounds__(256)
void reduce_kernel(const float* __restrict__ part, float* __restrict__ out)
{
    const int i = blockIdx.x * 256 + threadIdx.x;     // 0 .. 131071
    float s = 0.f;
    #pragma unroll 8
    for (int sp = 0; sp < NSPLIT; ++sp)
        s += part[(size_t)sp * (B_SZ * S_SZ) + i];
    out[i] = s;
}

// ---------------------------------------------------------------------------
// Fallback (round-0 kernel, atomics) if ws is too small.
// ---------------------------------------------------------------------------
#define FB_MT 256
#define FB_BT 64
#define SGF_STRIDE 68
__global__ __launch_bounds__(NTHR, 2)
void cpsf_fused_fallback(const float* __restrict__ z,
                         const float* __restrict__ z_j,
                         const float* __restrict__ vec_d_j,
                         const float* __restrict__ T_hat,
                         const float* __restrict__ alpha_j,
                         const float* __restrict__ sigma_par,
                         const float* __restrict__ sigma_perp,
                         float* __restrict__ out)
{
    __shared__ float sZ[FB_BT * N_SZ];
    __shared__ float sZn[FB_BT];
    __shared__ float sG[FB_MT * SGF_STRIDE];

    const int t     = threadIdx.x;
    const int m0    = blockIdx.x * FB_MT;
    const int bbase = blockIdx.y * FB_BT;

    {
        const float4* z4 = (const float4*)z + (size_t)bbase * (N_SZ / 4);
        float4* s4 = (float4*)sZ;
        #pragma unroll
        for (int i = t; i < FB_BT * N_SZ / 4; i += NTHR) s4[i] = z4[i];
    }
    const int m = m0 + t;
    float zj[N_SZ], dv[N_SZ];
    {
        const float4* a4 = (const float4*)(z_j     + (size_t)m * N_SZ);
        const float4* d4 = (const float4*)(vec_d_j + (size_t)m * N_SZ);
        #pragma unroll
        for (int i = 0; i < N_SZ / 4; ++i) {
            float4 av = a4[i], dw = d4[i];
            zj[4*i+0]=av.x; zj[4*i+1]=av.y; zj[4*i+2]=av.z; zj[4*i+3]=av.w;
            dv[4*i+0]=dw.x; dv[4*i+1]=dw.y; dv[4*i+2]=dw.z; dv[4*i+3]=dw.w;
        }
    }
    float zjn = 0.f, dnsq = 0.f, zjd = 0.f;
    #pragma unroll
    for (int n = 0; n < N_SZ; ++n) {
        zjn += zj[n]*zj[n]; dnsq += dv[n]*dv[n]; zjd += zj[n]*dv[n];
    }
    const float dn = sqrtf(dnsq);
    const float inv_dn = (dn > 1e-6f) ? (1.0f / dn) : 0.0f;
    const float P0 = zjd * inv_dn;
    const float tiny = 1.1920928955078125e-07f;
    const float sp  = fmaxf(sigma_par[m],  tiny);
    const float spp = fmaxf(sigma_perp[m], tiny);
    const float wperp = 1.0f / (spp * spp);
    const float wdiff = 1.0f / (sp * sp) - wperp;
    const float Cc = wperp * zjn;
    const float al = alpha_j[m];

    __syncthreads();
    if (t < FB_BT) {
        float s = 0.f;
        #pragma unroll
        for (int n = 0; n < N_SZ; ++n) { float v = sZ[t*N_SZ+n]; s += v*v; }
        sZn[t] = s;
    }
    __syncthreads();

    const float PI_F = 3.14159274101257324f;
    for (int bq = 0; bq < FB_BT / 4; ++bq) {
        float g[4];
        #pragma unroll
        for (int k = 0; k < 4; ++k) {
            const int b = bq*4 + k;
            float s1 = 0.f, sd = 0.f;
            #pragma unroll
            for (int n = 0; n < N_SZ; ++n) {
                const float zv = sZ[b*N_SZ+n];
                s1 += zv*zj[n]; sd += zv*dv[n];
            }
            const float p = sd*inv_dn - P0;
            float qv = wperp*sZn[b] - 2.0f*wperp*s1 + Cc + wdiff*p*p;
            qv = fminf(qv, 25.0f);
            g[k] = al * __expf(-PI_F*qv);
        }
        *(float4*)&sG[t*SGF_STRIDE + bq*4] = make_float4(g[0],g[1],g[2],g[3]);
    }
    __syncthreads();

    const int sg = t & 15, bg = t >> 4;
    const int b0 = bg*4, s0 = sg*8;
    float acc[4][8];
    #pragma unroll
    for (int i = 0; i < 4; ++i)
        #pragma unroll
        for (int j = 0; j < 8; ++j) acc[i][j] = 0.f;
    const float4* th4 = (const float4*)T_hat + (size_t)m0*(S_SZ/4) + sg*2;
    for (int mm = 0; mm < FB_MT; ++mm) {
        const float4 g4 = *(const float4*)&sG[mm*SGF_STRIDE + b0];
        const float4 ta = th4[(size_t)mm*(S_SZ/4)];
        const float4 tb = th4[(size_t)mm*(S_SZ/4)+1];
        const float gg[4] = {g4.x,g4.y,g4.z,g4.w};
        const float tv[8] = {ta.x,ta.y,ta.z,ta.w,tb.x,tb.y,tb.z,tb.w};
        #pragma unroll
        for (int i = 0; i < 4; ++i)
            #pragma unroll
            for (int j = 0; j < 8; ++j) acc[i][j] += gg[i]*tv[j];
    }
    float* op = out + (size_t)(bbase + b0)*S_SZ + s0;
    #pragma unroll
    for (int i = 0; i < 4; ++i)
        #pragma unroll
        for (int j = 0; j < 8; ++j)
            unsafeAtomicAdd(&op[i*S_SZ + j], acc[i][j]);
}

extern "C" void kernel_launch(void* const* d_in, const int* in_sizes, int n_in,
                              void* d_out, int out_size, void* d_ws, size_t ws_size,
                              hipStream_t stream) {
    (void)in_sizes; (void)n_in; (void)out_size;

    const float* z          = (const float*)d_in[0];
    const float* z_j        = (const float*)d_in[1];
    const float* vec_d_j    = (const float*)d_in[2];
    const float* T_hat_j    = (const float*)d_in[3];
    const float* alpha_j    = (const float*)d_in[4];
    const float* sigma_par  = (const float*)d_in[5];
    const float* sigma_perp = (const float*)d_in[6];
    float* out = (float*)d_out;

    if (ws_size >= WS_NEED) {
        char*  ws   = (char*)d_ws;
        float* part = (float*)(ws + WS_PART);

        prep_kernel<<<dim3(548), 256, 0, stream>>>(
            T_hat_j, z, z_j, vec_d_j, alpha_j, sigma_par, sigma_perp, ws);

        dim3 grid(NSPLIT, B_SZ / BT);   // 32 x 32 = 1024 blocks = 4/CU
        cpsf_main_kernel<<<grid, NTHR, 0, stream>>>(ws, part);

        reduce_kernel<<<dim3(B_SZ * S_SZ / 256), 256, 0, stream>>>(part, out);
    } else {
        hipMemsetAsync(out, 0, (size_t)B_SZ * S_SZ * sizeof(float), stream);
        dim3 grid(M_SZ / FB_MT, B_SZ / FB_BT);
        cpsf_fused_fallback<<<grid, NTHR, 0, stream>>>(
            z, z_j, vec_d_j, T_hat_j, alpha_j, sigma_par, sigma_perp, out);
    }
}

// Round 5
// 91.934 us; speedup vs baseline: 1.0483x; 1.0483x over previous
//
#include <hip/hip_runtime.h>
#include <hip/hip_bf16.h>
#include <math.h>

// Problem constants (fixed by the reference):
#define B_SZ 1024
#define M_SZ 8192
#define N_SZ 32
#define S_SZ 128

#define BT    32    // b-rows per main block
#define NTHR  256
#define NSPLIT 16   // m-splits; main grid = NSPLIT x (B/BT) = 16x32 = 512 = 2/CU
#define MT    (M_SZ / NSPLIT)   // 512 m per block, processed in 2 chunks of 256
#define MCH   256               // m-chunk (sG capacity)

#define SG_STRIDE 264   // bf16 elems per sG row: 256 + 8 pad (row = 528 B)

typedef __bf16 bf16x8 __attribute__((ext_vector_type(8)));
typedef float  f32x4  __attribute__((ext_vector_type(4)));

#if defined(__has_builtin)
#if __has_builtin(__builtin_amdgcn_exp2f)
#define EXP2F(x) __builtin_amdgcn_exp2f(x)
#else
#define EXP2F(x) exp2f(x)
#endif
#else
#define EXP2F(x) exp2f(x)
#endif

// -pi * log2(e), and the q<=25 clamp mapped into the exponent domain
#define NEG_PI_LOG2E  (-4.5323601722717285f)
#define E_CLAMP       (-113.30900573730469f)

// ---- workspace layout (bytes) ----
#define WS_TSWZ   ((size_t)0)                          // 2 MB  frag-linear bf16 T_hat
#define WS_ZJBF   ((size_t)2 * 1024 * 1024)            // 512 KB bf16 z_j [M][32]
#define WS_DVBF   (WS_ZJBF + (size_t)M_SZ * N_SZ * 2)  // 512 KB bf16 d_hat [M][32]
#define WS_MCONST (WS_DVBF + (size_t)M_SZ * N_SZ * 2)  // 256 KB f32 [M][8] consts
#define WS_ZBF    (WS_MCONST + (size_t)M_SZ * 8 * 4)   // 64 KB  bf16 z [B][32]
#define WS_ZN     (WS_ZBF + (size_t)B_SZ * N_SZ * 2)   // 4 KB   f32 |z_b|^2
#define WS_NEED   (WS_ZN + (size_t)B_SZ * 4)           // ~3.4 MB

// ---------------------------------------------------------------------------
// prep (550 blocks x 256):
//  blocks [0,512):   T_hat fp32 [M][S] -> frag-linear bf16 (16 B = one lane's
//                    B-frag: group g -> mc=g>>9, ns=(g>>6)&7, lane=g&63 holds
//                    B[k=mc*32+(lane>>4)*8+j][s=ns*16+(lane&15)])
//  blocks [512,544): per-m: bf16 z_j row, bf16 d_hat row (EPS gate), consts
//                    {A=-pi*log2e*wperp, Cm=A*|zj|^2, Dm=-pi*log2e*wdiff, P0, alpha}
//  blocks [544,548): per-b: bf16 z row + |z|^2
//  blocks [548,550): zero d_out (main accumulates into it with atomics)
// ---------------------------------------------------------------------------
__global__ __launch_bounds__(256)
void prep_kernel(const float* __restrict__ T,
                 const float* __restrict__ z,
                 const float* __restrict__ zj_in,
                 const float* __restrict__ dv_in,
                 const float* __restrict__ alpha_j,
                 const float* __restrict__ sigma_par,
                 const float* __restrict__ sigma_perp,
                 char* __restrict__ ws,
                 float* __restrict__ out)
{
    const int bx = blockIdx.x;
    const int t  = threadIdx.x;

    if (bx < 512) {                       // ---- T swizzle ----
        const int g    = bx * 256 + t;    // 0 .. 131071
        const int mc   = g >> 9;
        const int ns   = (g >> 6) & 7;
        const int lane = g & 63;
        const int c    = lane & 15;
        const int q    = lane >> 4;
        const float* src = T + (size_t)(mc * 32 + q * 8) * S_SZ + ns * 16 + c;
        bf16x8 v;
        #pragma unroll
        for (int j = 0; j < 8; ++j) v[j] = (__bf16)src[(size_t)j * S_SZ];
        *(bf16x8*)(ws + WS_TSWZ + (size_t)g * 16) = v;
    } else if (bx < 544) {                // ---- per-m prep ----
        const int m = (bx - 512) * 256 + t;
        float a[N_SZ], d[N_SZ];
        const float4* a4 = (const float4*)(zj_in + (size_t)m * N_SZ);
        const float4* d4 = (const float4*)(dv_in + (size_t)m * N_SZ);
        #pragma unroll
        for (int i = 0; i < N_SZ / 4; ++i) {
            float4 av = a4[i], dw = d4[i];
            a[4*i+0]=av.x; a[4*i+1]=av.y; a[4*i+2]=av.z; a[4*i+3]=av.w;
            d[4*i+0]=dw.x; d[4*i+1]=dw.y; d[4*i+2]=dw.z; d[4*i+3]=dw.w;
        }
        float zjn = 0.f, dnsq = 0.f, zjd = 0.f;
        #pragma unroll
        for (int n = 0; n < N_SZ; ++n) {
            zjn += a[n]*a[n]; dnsq += d[n]*d[n]; zjd += a[n]*d[n];
        }
        const float dn  = sqrtf(dnsq);
        const float inv = (dn > 1e-6f) ? (1.0f / dn) : 0.0f;   // EPS gate -> proj=0
        __bf16* zjb = (__bf16*)(ws + WS_ZJBF) + (size_t)m * N_SZ;
        __bf16* dvb = (__bf16*)(ws + WS_DVBF) + (size_t)m * N_SZ;
        #pragma unroll
        for (int i = 0; i < 4; ++i) {
            bf16x8 vz, vd;
            #pragma unroll
            for (int j = 0; j < 8; ++j) {
                vz[j] = (__bf16)a[i*8+j];
                vd[j] = (__bf16)(d[i*8+j] * inv);
            }
            *(bf16x8*)(zjb + i*8) = vz;
            *(bf16x8*)(dvb + i*8) = vd;
        }
        const float tiny = 1.1920928955078125e-07f;
        const float sp  = fmaxf(sigma_par[m],  tiny);
        const float spp = fmaxf(sigma_perp[m], tiny);
        const float wperp = 1.0f / (spp * spp);
        const float wdiff = 1.0f / (sp * sp) - wperp;
        const float A = NEG_PI_LOG2E * wperp;
        float* mc8 = (float*)(ws + WS_MCONST) + (size_t)m * 8;
        *(f32x4*)mc8       = (f32x4){A, A * zjn, NEG_PI_LOG2E * wdiff, zjd * inv};
        *(f32x4*)(mc8 + 4) = (f32x4){alpha_j[m], 0.f, 0.f, 0.f};
    } else if (bx < 548) {                // ---- per-b prep ----
        const int b = (bx - 544) * 256 + t;   // 0..1023
        float v[N_SZ];
        const float4* z4 = (const float4*)(z + (size_t)b * N_SZ);
        #pragma unroll
        for (int i = 0; i < N_SZ / 4; ++i) {
            float4 w4 = z4[i];
            v[4*i+0]=w4.x; v[4*i+1]=w4.y; v[4*i+2]=w4.z; v[4*i+3]=w4.w;
        }
        float zn = 0.f;
        #pragma unroll
        for (int n = 0; n < N_SZ; ++n) zn += v[n]*v[n];
        __bf16* zb = (__bf16*)(ws + WS_ZBF) + (size_t)b * N_SZ;
        #pragma unroll
        for (int i = 0; i < 4; ++i) {
            bf16x8 vz;
            #pragma unroll
            for (int j = 0; j < 8; ++j) vz[j] = (__bf16)v[i*8+j];
            *(bf16x8*)(zb + i*8) = vz;
        }
        ((float*)(ws + WS_ZN))[b] = zn;
    } else {                              // ---- zero d_out (0.5 MB, 2 blocks) ----
        f32x4* o4 = (f32x4*)out;
        const int base = (bx - 548) * (B_SZ * S_SZ / 4 / 2);   // halves of 32768 x f32x4
        #pragma unroll 4
        for (int i = t; i < B_SZ * S_SZ / 4 / 2; i += 256)
            o4[base + i] = (f32x4){0.f, 0.f, 0.f, 0.f};
    }
}

// ---------------------------------------------------------------------------
// main: per block (mx, by): 512 m x 32 b, two 256-m chunks.
// Per chunk: scores via MFMA + exp2 epilogue -> sG (LDS), then PV via MFMA
// (acc registers persist across chunks). Epilogue: fp32 atomic add to out
// (out zeroed by prep; 16 atomics/thread, target is L2-resident 0.5 MB).
// Grid (NSPLIT=16, B/BT=32) = 512 blocks = 2/CU. LDS = 16.9 KB.
// Phase 1: wave w -> b-half (w&1), m-tiles (w>>1)*8 + [0,8).
// Phase 2: wave w -> s-tiles {2w,2w+1} x both b-tiles.
// ---------------------------------------------------------------------------
__global__ __launch_bounds__(NTHR, 4)
void cpsf_main_kernel(const char* __restrict__ ws_ro, float* __restrict__ out)
{
    __shared__ __align__(16) __bf16 sG[BT * SG_STRIDE];   // 16.9 KB: gains [b][m_local]

    const int t     = threadIdx.x;
    const int lane  = t & 63;
    const int w     = t >> 6;          // wave 0..3
    const int q     = lane >> 4;       // quad 0..3
    const int c     = lane & 15;
    const int mx    = blockIdx.x;
    const int bbase = blockIdx.y * BT;

    const __bf16* zbf   = (const __bf16*)(ws_ro + WS_ZBF);
    const __bf16* zjbf  = (const __bf16*)(ws_ro + WS_ZJBF);
    const __bf16* dvbf  = (const __bf16*)(ws_ro + WS_DVBF);
    const float*  mcst  = (const float*)(ws_ro + WS_MCONST);
    const float*  znp   = (const float*)(ws_ro + WS_ZN);
    const char*   Tswz  = ws_ro + WS_TSWZ;

    const int wb  = w & 1;             // which 16-row b-half this wave scores
    const int mt0 = (w >> 1) * 8;      // which 8 m-tiles (of 16 per chunk)

    // A-frag: z[b = bbase + wb*16 + c][k = q*8 + j] — reused across both chunks
    const bf16x8 zA  = *(const bf16x8*)(zbf + ((size_t)(bbase + wb*16 + c) * N_SZ + q*8));
    const f32x4  zn4 = *(const f32x4*)(znp + bbase + wb*16 + q*4);

    f32x4 acc[2][2];                   // [b-tile][s-subtile] — persists across chunks
    #pragma unroll
    for (int bt = 0; bt < 2; ++bt)
        #pragma unroll
        for (int i = 0; i < 2; ++i) acc[bt][i] = (f32x4){0.f,0.f,0.f,0.f};

    for (int chunk = 0; chunk < MT / MCH; ++chunk) {
        const int m0 = mx * MT + chunk * MCH;

        if (chunk) __syncthreads();    // protect sG reuse from previous phase 2

        // ---- Phase 1: scores + gains for this chunk ----
        #pragma unroll 4
        for (int ti = 0; ti < 8; ++ti) {
            const int tile = mt0 + ti;
            const int mg   = m0 + tile*16 + c;
            const bf16x8 bz = *(const bf16x8*)(zjbf + (size_t)mg * N_SZ + q*8);
            const bf16x8 bd = *(const bf16x8*)(dvbf + (size_t)mg * N_SZ + q*8);
            f32x4 s1 = __builtin_amdgcn_mfma_f32_16x16x32_bf16(zA, bz, (f32x4){0.f,0.f,0.f,0.f}, 0, 0, 0);
            f32x4 sd = __builtin_amdgcn_mfma_f32_16x16x32_bf16(zA, bd, (f32x4){0.f,0.f,0.f,0.f}, 0, 0, 0);
            const float* mc8 = mcst + (size_t)mg * 8;
            const f32x4 mc0 = *(const f32x4*)mc8;   // {A, Cm, Dm, P0}
            const float al  = mc8[4];
            #pragma unroll
            for (int reg = 0; reg < 4; ++reg) {
                // e = A*(zn - 2*s1) + Cm + Dm*(sd-P0)^2  (log2 domain, incl -pi)
                const float t1 = fmaf(s1[reg], -2.0f, zn4[reg]);
                float e = fmaf(mc0[0], t1, mc0[1]);
                const float p = sd[reg] - mc0[3];
                e = fmaf(mc0[2] * p, p, e);
                e = fmaxf(e, E_CLAMP);               // q <= 25 clamp
                const float g = al * EXP2F(e);
                // D[row=q*4+reg][col=c] -> gain[b-local = wb*16+q*4+reg][m-local]
                sG[(size_t)(wb*16 + q*4 + reg) * SG_STRIDE + tile*16 + c] = (__bf16)g;
            }
        }
        __syncthreads();

        // ---- Phase 2: PV for this chunk. Wave w: s-tiles {2w,2w+1}, both b-tiles.
        #pragma unroll
        for (int kc = 0; kc < MCH / 32; ++kc) {
            const int mc = (mx * MT + chunk * MCH) / 32 + kc;   // global 32-m chunk
            bf16x8 bfr[2];
            #pragma unroll
            for (int i = 0; i < 2; ++i)
                bfr[i] = *(const bf16x8*)(Tswz + ((size_t)(mc*8 + w*2 + i) * 64 + lane) * 16);
            #pragma unroll
            for (int bt = 0; bt < 2; ++bt) {
                // A-frag: G[b = bt*16 + c][k = kc*32 + q*8 + j]
                const bf16x8 a = *(const bf16x8*)((const char*)sG
                                  + (size_t)(bt*16 + c) * (SG_STRIDE*2) + kc*64 + q*16);
                #pragma unroll
                for (int i = 0; i < 2; ++i)
                    acc[bt][i] = __builtin_amdgcn_mfma_f32_16x16x32_bf16(a, bfr[i], acc[bt][i], 0, 0, 0);
            }
        }
    }

    // ---- Epilogue: fp32 atomic add into out (zeroed by prep). ----
    // D[row=q*4+reg][col=c]; 16 lane-atomics/thread, 2.1M total into 0.5 MB (L2).
    #pragma unroll
    for (int bt = 0; bt < 2; ++bt) {
        float* op = out + (size_t)(bbase + bt*16 + q*4) * S_SZ + w*32 + c;
        #pragma unroll
        for (int i = 0; i < 2; ++i)
            #pragma unroll
            for (int reg = 0; reg < 4; ++reg)
                unsafeAtomicAdd(&op[(size_t)reg * S_SZ + i*16], acc[bt][i][reg]);
    }
}

// ---------------------------------------------------------------------------
// Fallback (round-0 kernel, atomics) if ws is too small.
// ---------------------------------------------------------------------------
#define FB_MT 256
#define FB_BT 64
#define SGF_STRIDE 68
__global__ __launch_bounds__(NTHR, 2)
void cpsf_fused_fallback(const float* __restrict__ z,
                         const float* __restrict__ z_j,
                         const float* __restrict__ vec_d_j,
                         const float* __restrict__ T_hat,
                         const float* __restrict__ alpha_j,
                         const float* __restrict__ sigma_par,
                         const float* __restrict__ sigma_perp,
                         float* __restrict__ out)
{
    __shared__ float sZ[FB_BT * N_SZ];
    __shared__ float sZn[FB_BT];
    __shared__ float sG[FB_MT * SGF_STRIDE];

    const int t     = threadIdx.x;
    const int m0    = blockIdx.x * FB_MT;
    const int bbase = blockIdx.y * FB_BT;

    {
        const float4* z4 = (const float4*)z + (size_t)bbase * (N_SZ / 4);
        float4* s4 = (float4*)sZ;
        #pragma unroll
        for (int i = t; i < FB_BT * N_SZ / 4; i += NTHR) s4[i] = z4[i];
    }
    const int m = m0 + t;
    float zj[N_SZ], dv[N_SZ];
    {
        const float4* a4 = (const float4*)(z_j     + (size_t)m * N_SZ);
        const float4* d4 = (const float4*)(vec_d_j + (size_t)m * N_SZ);
        #pragma unroll
        for (int i = 0; i < N_SZ / 4; ++i) {
            float4 av = a4[i], dw = d4[i];
            zj[4*i+0]=av.x; zj[4*i+1]=av.y; zj[4*i+2]=av.z; zj[4*i+3]=av.w;
            dv[4*i+0]=dw.x; dv[4*i+1]=dw.y; dv[4*i+2]=dw.z; dv[4*i+3]=dw.w;
        }
    }
    float zjn = 0.f, dnsq = 0.f, zjd = 0.f;
    #pragma unroll
    for (int n = 0; n < N_SZ; ++n) {
        zjn += zj[n]*zj[n]; dnsq += dv[n]*dv[n]; zjd += zj[n]*dv[n];
    }
    const float dn = sqrtf(dnsq);
    const float inv_dn = (dn > 1e-6f) ? (1.0f / dn) : 0.0f;
    const float P0 = zjd * inv_dn;
    const float tiny = 1.1920928955078125e-07f;
    const float sp  = fmaxf(sigma_par[m],  tiny);
    const float spp = fmaxf(sigma_perp[m], tiny);
    const float wperp = 1.0f / (spp * spp);
    const float wdiff = 1.0f / (sp * sp) - wperp;
    const float Cc = wperp * zjn;
    const float al = alpha_j[m];

    __syncthreads();
    if (t < FB_BT) {
        float s = 0.f;
        #pragma unroll
        for (int n = 0; n < N_SZ; ++n) { float v = sZ[t*N_SZ+n]; s += v*v; }
        sZn[t] = s;
    }
    __syncthreads();

    const float PI_F = 3.14159274101257324f;
    for (int bq = 0; bq < FB_BT / 4; ++bq) {
        float g[4];
        #pragma unroll
        for (int k = 0; k < 4; ++k) {
            const int b = bq*4 + k;
            float s1 = 0.f, sd = 0.f;
            #pragma unroll
            for (int n = 0; n < N_SZ; ++n) {
                const float zv = sZ[b*N_SZ+n];
                s1 += zv*zj[n]; sd += zv*dv[n];
            }
            const float p = sd*inv_dn - P0;
            float qv = wperp*sZn[b] - 2.0f*wperp*s1 + Cc + wdiff*p*p;
            qv = fminf(qv, 25.0f);
            g[k] = al * __expf(-PI_F*qv);
        }
        *(float4*)&sG[t*SGF_STRIDE + bq*4] = make_float4(g[0],g[1],g[2],g[3]);
    }
    __syncthreads();

    const int sg = t & 15, bg = t >> 4;
    const int b0 = bg*4, s0 = sg*8;
    float acc[4][8];
    #pragma unroll
    for (int i = 0; i < 4; ++i)
        #pragma unroll
        for (int j = 0; j < 8; ++j) acc[i][j] = 0.f;
    const float4* th4 = (const float4*)T_hat + (size_t)m0*(S_SZ/4) + sg*2;
    for (int mm = 0; mm < FB_MT; ++mm) {
        const float4 g4 = *(const float4*)&sG[mm*SGF_STRIDE + b0];
        const float4 ta = th4[(size_t)mm*(S_SZ/4)];
        const float4 tb = th4[(size_t)mm*(S_SZ/4)+1];
        const float gg[4] = {g4.x,g4.y,g4.z,g4.w};
        const float tv[8] = {ta.x,ta.y,ta.z,ta.w,tb.x,tb.y,tb.z,tb.w};
        #pragma unroll
        for (int i = 0; i < 4; ++i)
            #pragma unroll
            for (int j = 0; j < 8; ++j) acc[i][j] += gg[i]*tv[j];
    }
    float* op = out + (size_t)(bbase + b0)*S_SZ + s0;
    #pragma unroll
    for (int i = 0; i < 4; ++i)
        #pragma unroll
        for (int j = 0; j < 8; ++j)
            unsafeAtomicAdd(&op[i*S_SZ + j], acc[i][j]);
}

extern "C" void kernel_launch(void* const* d_in, const int* in_sizes, int n_in,
                              void* d_out, int out_size, void* d_ws, size_t ws_size,
                              hipStream_t stream) {
    (void)in_sizes; (void)n_in; (void)out_size;

    const float* z          = (const float*)d_in[0];
    const float* z_j        = (const float*)d_in[1];
    const float* vec_d_j    = (const float*)d_in[2];
    const float* T_hat_j    = (const float*)d_in[3];
    const float* alpha_j    = (const float*)d_in[4];
    const float* sigma_par  = (const float*)d_in[5];
    const float* sigma_perp = (const float*)d_in[6];
    float* out = (float*)d_out;

    if (ws_size >= WS_NEED) {
        char* ws = (char*)d_ws;

        // dispatch 1: all staging + zero d_out
        prep_kernel<<<dim3(550), 256, 0, stream>>>(
            T_hat_j, z, z_j, vec_d_j, alpha_j, sigma_par, sigma_perp, ws, out);

        // dispatch 2: fused scores + PV + atomic epilogue
        dim3 grid(NSPLIT, B_SZ / BT);   // 16 x 32 = 512 blocks = 2/CU
        cpsf_main_kernel<<<grid, NTHR, 0, stream>>>(ws, out);
    } else {
        hipMemsetAsync(out, 0, (size_t)B_SZ * S_SZ * sizeof(float), stream);
        dim3 grid(M_SZ / FB_MT, B_SZ / FB_BT);
        cpsf_fused_fallback<<<grid, NTHR, 0, stream>>>(
            z, z_j, vec_d_j, T_hat_j, alpha_j, sigma_par, sigma_perp, out);
    }
}